// Round 3
// baseline (321.960 us; speedup 1.0000x reference)
//
#include <hip/hip_runtime.h>

typedef __attribute__((ext_vector_type(8))) short short8;
typedef __attribute__((ext_vector_type(4))) float f32x4;
typedef __attribute__((ext_vector_type(4))) unsigned short us4;
typedef unsigned short ushort_t;
typedef unsigned int uint_t;

// fence: forbid compile-time reordering of LDS ops across this point and
// drain outstanding DS ops (rule #18: asm waitcnt needs sched_barrier after)
#define LDS_FENCE()                                            \
  do {                                                         \
    asm volatile("s_waitcnt lgkmcnt(0)" ::: "memory");         \
    __builtin_amdgcn_sched_barrier(0);                         \
  } while (0)

__device__ __forceinline__ ushort_t f2b(float f) {
  union { float f; uint_t u; } v; v.f = f;
  return (ushort_t)((v.u + 0x7fffu + ((v.u >> 16) & 1u)) >> 16);
}

// ---------------- convert x: f32 -> bf16, 4 elems/thread ----------------
__global__ void cvt_x_kernel(const float* __restrict__ x, ushort_t* __restrict__ xb, int n4) {
  int i = blockIdx.x * blockDim.x + threadIdx.x;
  if (i >= n4) return;
  float4 v = ((const float4*)x)[i];
  ushort4 o;
  o.x = f2b(v.x); o.y = f2b(v.y); o.z = f2b(v.z); o.w = f2b(v.w);
  ((ushort4*)xb)[i] = o;
}

// ------- convert + transpose W [512][512] f32 -> WT [512][512] bf16 -------
__global__ void cvt_wt_kernel(const float* __restrict__ W0, const float* __restrict__ W1,
                              const float* __restrict__ W2, const float* __restrict__ W3,
                              ushort_t* __restrict__ T0, ushort_t* __restrict__ T1,
                              ushort_t* __restrict__ T2, ushort_t* __restrict__ T3) {
  const float* W; ushort_t* T;
  switch (blockIdx.z) {
    case 0: W = W0; T = T0; break;
    case 1: W = W1; T = T1; break;
    case 2: W = W2; T = T2; break;
    default: W = W3; T = T3; break;
  }
  int idx = blockIdx.x * 256 + threadIdx.x;  // 0..262143
  int n = idx >> 9, k = idx & 511;
  T[idx] = f2b(W[k * 512 + n]);              // WT[n][k] = W[k][n]
}

// ---------------- QKV projection GEMM (bf16 MFMA, f32 accum) ----------------
// A [8192][512] bf16 row-major; BT [512][512] bf16 (= W^T) row-major.
// z=0 -> Q natural bf16 [B*S][512]; z=1 -> K natural; z=2 -> V transposed [B*H*Dh][S]
__global__ __launch_bounds__(256) void gemm_qkv_kernel(
    const ushort_t* __restrict__ A,
    const ushort_t* __restrict__ WqT, const ushort_t* __restrict__ WkT,
    const ushort_t* __restrict__ WvT,
    ushort_t* __restrict__ Qo, ushort_t* __restrict__ Ko, ushort_t* __restrict__ VTo) {
  const int K = 512, N = 512, S = 4096;
  const ushort_t* BT; ushort_t* out; int mode;
  switch (blockIdx.z) {
    case 0: BT = WqT; out = Qo;  mode = 0; break;
    case 1: BT = WkT; out = Ko;  mode = 0; break;
    default: BT = WvT; out = VTo; mode = 1; break;
  }
  int tid = threadIdx.x, lane = tid & 63, w = tid >> 6;
  int g = lane >> 4, ln = lane & 15;
  int wr = w >> 1, wc = w & 1;
  int m0 = blockIdx.y * 128 + wr * 64;
  int n0 = blockIdx.x * 64 + wc * 32;

  f32x4 acc[4][2];
  const f32x4 zz = {0.f, 0.f, 0.f, 0.f};
#pragma unroll
  for (int i = 0; i < 4; ++i)
#pragma unroll
    for (int j = 0; j < 2; ++j) acc[i][j] = zz;

  const ushort_t* Ab = A + (size_t)(m0 + ln) * K + g * 8;
  const ushort_t* Bb = BT + (size_t)(n0 + ln) * K + g * 8;

  for (int kc = 0; kc < K; kc += 32) {
    short8 af[4], bfr[2];
#pragma unroll
    for (int mt = 0; mt < 4; ++mt) af[mt] = *(const short8*)(Ab + (size_t)mt * 16 * K + kc);
#pragma unroll
    for (int nt = 0; nt < 2; ++nt) bfr[nt] = *(const short8*)(Bb + (size_t)nt * 16 * K + kc);
#pragma unroll
    for (int mt = 0; mt < 4; ++mt)
#pragma unroll
      for (int nt = 0; nt < 2; ++nt)
        acc[mt][nt] = __builtin_amdgcn_mfma_f32_16x16x32_bf16(af[mt], bfr[nt], acc[mt][nt], 0, 0, 0);
  }

  if (mode == 0) {
#pragma unroll
    for (int mt = 0; mt < 4; ++mt)
#pragma unroll
      for (int nt = 0; nt < 2; ++nt)
#pragma unroll
        for (int jj = 0; jj < 4; ++jj) {
          int m = m0 + mt * 16 + 4 * g + jj;
          int n = n0 + nt * 16 + ln;
          out[(size_t)m * N + n] = f2b(acc[mt][nt][jj]);
        }
  } else {
#pragma unroll
    for (int mt = 0; mt < 4; ++mt)
#pragma unroll
      for (int nt = 0; nt < 2; ++nt)
#pragma unroll
        for (int jj = 0; jj < 4; ++jj) {
          int m = m0 + mt * 16 + 4 * g + jj;   // m = b*4096 + s
          int u = n0 + nt * 16 + ln;           // u = h*64 + d
          int b = m >> 12, s = m & 4095;
          int h = u >> 6, d = u & 63;
          out[((size_t)((b * 8 + h) * 64 + d)) * S + s] = f2b(acc[mt][nt][jj]);
        }
  }
}

// ---------------- output projection GEMM: f32 out ----------------
__global__ __launch_bounds__(256) void gemm_ao_kernel(
    const ushort_t* __restrict__ A, const ushort_t* __restrict__ BT,
    float* __restrict__ out) {
  const int K = 512, N = 512;
  int tid = threadIdx.x, lane = tid & 63, w = tid >> 6;
  int g = lane >> 4, ln = lane & 15;
  int wr = w >> 1, wc = w & 1;
  int m0 = blockIdx.y * 128 + wr * 64;
  int n0 = blockIdx.x * 64 + wc * 32;

  f32x4 acc[4][2];
  const f32x4 zz = {0.f, 0.f, 0.f, 0.f};
#pragma unroll
  for (int i = 0; i < 4; ++i)
#pragma unroll
    for (int j = 0; j < 2; ++j) acc[i][j] = zz;

  const ushort_t* Ab = A + (size_t)(m0 + ln) * K + g * 8;
  const ushort_t* Bb = BT + (size_t)(n0 + ln) * K + g * 8;

  for (int kc = 0; kc < K; kc += 32) {
    short8 af[4], bfr[2];
#pragma unroll
    for (int mt = 0; mt < 4; ++mt) af[mt] = *(const short8*)(Ab + (size_t)mt * 16 * K + kc);
#pragma unroll
    for (int nt = 0; nt < 2; ++nt) bfr[nt] = *(const short8*)(Bb + (size_t)nt * 16 * K + kc);
#pragma unroll
    for (int mt = 0; mt < 4; ++mt)
#pragma unroll
      for (int nt = 0; nt < 2; ++nt)
        acc[mt][nt] = __builtin_amdgcn_mfma_f32_16x16x32_bf16(af[mt], bfr[nt], acc[mt][nt], 0, 0, 0);
  }
#pragma unroll
  for (int mt = 0; mt < 4; ++mt)
#pragma unroll
    for (int nt = 0; nt < 2; ++nt)
#pragma unroll
      for (int jj = 0; jj < 4; ++jj) {
        int m = m0 + mt * 16 + 4 * g + jj;
        int n = n0 + nt * 16 + ln;
        out[(size_t)m * N + n] = acc[mt][nt][jj];
      }
}

// ---------------- flash attention ----------------
// grid (S/64, H, B); 4 waves/block; wave w owns q rows [qb*64 + w*16, +16)
// Q,K natural bf16 [B*S][512]; VT bf16 [(b*8+h)*64 + d][4096]; CTX bf16 [B*S][512]
__global__ __launch_bounds__(256) void attn_kernel(
    const ushort_t* __restrict__ Qg, const ushort_t* __restrict__ Kg,
    const ushort_t* __restrict__ VTg, ushort_t* __restrict__ CTXg) {
  const int S = 4096, U = 512, DH = 64;
  int qb = blockIdx.x, h = blockIdx.y, b = blockIdx.z;
  int tid = threadIdx.x, lane = tid & 63, w = tid >> 6;
  int g = lane >> 4, ln = lane & 15;

  __shared__ ushort_t Kl[64 * 64];
  __shared__ ushort_t Vl[64 * 64];
  __shared__ ushort_t Pl[4][16 * 72];   // stride 72 u16 = 144 B (16B aligned)

  // Q fragments held in registers for the whole kernel
  const ushort_t* qp = Qg + ((size_t)b * S + qb * 64 + w * 16 + ln) * U + h * DH + g * 8;
  short8 qf0 = *(const short8*)qp;
  short8 qf1 = *(const short8*)(qp + 32);

  f32x4 acc[4];
  const f32x4 zz = {0.f, 0.f, 0.f, 0.f};
#pragma unroll
  for (int i = 0; i < 4; ++i) acc[i] = zz;
  float mrun = -INFINITY, lrun = 0.f;

  int r = tid >> 3;              // 0..31
  int c8 = (tid & 7) * 8;        // 0,8,..,56
  const ushort_t* kbase = Kg + ((size_t)b * S + r) * U + h * DH + c8;
  const ushort_t* vbase = VTg + ((size_t)((b * 8 + h) * 64 + r)) * S + c8;

  for (int it = 0; it < 64; ++it) {
    int kv0 = it * 64;
    // issue global loads before the barrier (overlap with previous tile's compute)
    uint4 k1 = *(const uint4*)(kbase + (size_t)kv0 * U);
    uint4 k2 = *(const uint4*)(kbase + (size_t)(kv0 + 32) * U);
    uint4 v1 = *(const uint4*)(vbase + kv0);
    uint4 v2 = *(const uint4*)(vbase + (size_t)32 * S + kv0);
    __syncthreads();   // previous tile fully consumed
    {
      int by1 = (r * 128 + c8 * 2) ^ ((r & 7) << 4);
      *(uint4*)((char*)Kl + by1) = k1;
      *(uint4*)((char*)Vl + by1) = v1;
      int r2 = r + 32;
      int by2 = (r2 * 128 + c8 * 2) ^ ((r2 & 7) << 4);
      *(uint4*)((char*)Kl + by2) = k2;
      *(uint4*)((char*)Vl + by2) = v2;
    }
    __syncthreads();   // tile staged

    // ---- S^T = K . Q^T  (rows = kv, cols = q) ----
    f32x4 st[4];
#pragma unroll
    for (int m = 0; m < 4; ++m) {
      int row = m * 16 + ln;
      short8 kf0 = *(const short8*)((char*)Kl + ((row * 128 + 16 * g) ^ ((row & 7) << 4)));
      short8 kf1 = *(const short8*)((char*)Kl + ((row * 128 + 64 + 16 * g) ^ ((row & 7) << 4)));
      st[m] = __builtin_amdgcn_mfma_f32_16x16x32_bf16(kf0, qf0, zz, 0, 0, 0);
      st[m] = __builtin_amdgcn_mfma_f32_16x16x32_bf16(kf1, qf1, st[m], 0, 0, 0);
    }

    // ---- online softmax; lane owns q-row (lane&15), 16 kv values ----
    float sc[16];
#pragma unroll
    for (int m = 0; m < 4; ++m)
#pragma unroll
      for (int jj = 0; jj < 4; ++jj) sc[m * 4 + jj] = st[m][jj] * 0.125f;

    float tmax = sc[0];
#pragma unroll
    for (int i = 1; i < 16; ++i) tmax = fmaxf(tmax, sc[i]);
    tmax = fmaxf(tmax, __shfl_xor(tmax, 16));
    tmax = fmaxf(tmax, __shfl_xor(tmax, 32));
    float mnew = fmaxf(mrun, tmax);
    float alpha = __expf(mrun - mnew);
    mrun = mnew;

    float ps = 0.f;
    ushort_t pb[16];
#pragma unroll
    for (int i = 0; i < 16; ++i) {
      float p = __expf(sc[i] - mnew);
      ps += p;
      pb[i] = f2b(p);
    }
    ps += __shfl_xor(ps, 16);
    ps += __shfl_xor(ps, 32);
    lrun = lrun * alpha + ps;

    // P -> LDS (wave-local buffer): P[q = ln][kv], 8-byte vector stores
#pragma unroll
    for (int m = 0; m < 4; ++m) {
      us4 pv;
      pv[0] = pb[m * 4 + 0]; pv[1] = pb[m * 4 + 1];
      pv[2] = pb[m * 4 + 2]; pv[3] = pb[m * 4 + 3];
      *(us4*)&Pl[w][ln * 72 + m * 16 + 4 * g] = pv;
    }
    LDS_FENCE();   // P stores must complete & stay ordered before P frag reads

    // rescale ctx accumulator (acc rows are q = 4g+jj); alpha via shfl, no LDS
    float av[4];
#pragma unroll
    for (int jj = 0; jj < 4; ++jj) av[jj] = __shfl(alpha, 4 * g + jj);
#pragma unroll
    for (int dt = 0; dt < 4; ++dt)
#pragma unroll
      for (int jj = 0; jj < 4; ++jj) acc[dt][jj] *= av[jj];

    // ---- PV: ctx += P . V  (A = P from LDS, B = VT from LDS) ----
#pragma unroll
    for (int c = 0; c < 2; ++c) {
      short8 pf = *(const short8*)&Pl[w][ln * 72 + 32 * c + 8 * g];
#pragma unroll
      for (int dt = 0; dt < 4; ++dt) {
        int row = dt * 16 + ln;
        short8 vf = *(const short8*)((char*)Vl + ((row * 128 + 64 * c + 16 * g) ^ ((row & 7) << 4)));
        acc[dt] = __builtin_amdgcn_mfma_f32_16x16x32_bf16(pf, vf, acc[dt], 0, 0, 0);
      }
    }
  }

  // finalize: divide by row sum (1/lrun via shfl), store ctx bf16 natural layout
  float inv_l = 1.f / lrun;
  float lv[4];
#pragma unroll
  for (int jj = 0; jj < 4; ++jj) lv[jj] = __shfl(inv_l, 4 * g + jj);
#pragma unroll
  for (int dt = 0; dt < 4; ++dt)
#pragma unroll
    for (int jj = 0; jj < 4; ++jj) {
      int s = qb * 64 + w * 16 + 4 * g + jj;
      int u = h * 64 + dt * 16 + ln;
      CTXg[((size_t)b * S + s) * U + u] = f2b(acc[dt][jj] * lv[jj]);
    }
}

extern "C" void kernel_launch(void* const* d_in, const int* in_sizes, int n_in,
                              void* d_out, int out_size, void* d_ws, size_t ws_size,
                              hipStream_t stream) {
  const float* x  = (const float*)d_in[0];
  const float* Wq = (const float*)d_in[1];
  const float* Wk = (const float*)d_in[2];
  const float* Wv = (const float*)d_in[3];
  const float* Wo = (const float*)d_in[4];
  float* out = (float*)d_out;

  ushort_t* ws  = (ushort_t*)d_ws;
  ushort_t* xb  = ws;                 // 4,194,304 elems (reused for CTX later)
  ushort_t* WqT = xb + 4194304;       // 262,144 each
  ushort_t* WkT = WqT + 262144;
  ushort_t* WvT = WkT + 262144;
  ushort_t* WoT = WvT + 262144;
  ushort_t* Qb  = WoT + 262144;       // 4,194,304 each
  ushort_t* Kb  = Qb + 4194304;
  ushort_t* VTb = Kb + 4194304;
  ushort_t* CTX = xb;                 // reuse: xb dead after gemm_qkv

  cvt_x_kernel<<<4096, 256, 0, stream>>>(x, xb, 1048576);
  cvt_wt_kernel<<<dim3(1024, 1, 4), 256, 0, stream>>>(Wq, Wk, Wv, Wo, WqT, WkT, WvT, WoT);
  gemm_qkv_kernel<<<dim3(8, 64, 3), 256, 0, stream>>>(xb, WqT, WkT, WvT, Qb, Kb, VTb);
  attn_kernel<<<dim3(64, 8, 2), 256, 0, stream>>>(Qb, Kb, VTb, CTX);
  gemm_ao_kernel<<<dim3(8, 64, 1), 256, 0, stream>>>(CTX, WoT, out);
}

// Round 5
// 250.034 us; speedup vs baseline: 1.2877x; 1.2877x over previous
//
#include <hip/hip_runtime.h>

typedef __attribute__((ext_vector_type(8))) short short8;
typedef __attribute__((ext_vector_type(4))) float f32x4;
typedef __attribute__((ext_vector_type(4))) unsigned short us4;
typedef unsigned short ushort_t;
typedef unsigned int uint_t;

typedef const __attribute__((address_space(1))) void* gas1;
typedef __attribute__((address_space(3))) void* las3;

// fence: forbid compile-time reordering of LDS ops across this point and
// drain outstanding DS ops (rule #18: asm waitcnt needs sched_barrier after)
#define LDS_FENCE()                                            \
  do {                                                         \
    asm volatile("s_waitcnt lgkmcnt(0)" ::: "memory");         \
    __builtin_amdgcn_sched_barrier(0);                         \
  } while (0)

__device__ __forceinline__ ushort_t f2b(float f) {
  union { float f; uint_t u; } v; v.f = f;
  return (ushort_t)((v.u + 0x7fffu + ((v.u >> 16) & 1u)) >> 16);
}

// pack 2 f32 -> 2 bf16 in one u32 (RNE) — T12 primitive
__device__ __forceinline__ uint_t cvtpk(float lo, float hi) {
  uint_t r;
  asm("v_cvt_pk_bf16_f32 %0, %1, %2" : "=v"(r) : "v"(lo), "v"(hi));
  return r;
}

__device__ __forceinline__ void gld_lds16(const ushort_t* g, void* l) {
  __builtin_amdgcn_global_load_lds((gas1)g, (las3)l, 16, 0, 0);
}

// ---------------- convert x: f32 -> bf16, 4 elems/thread ----------------
__global__ void cvt_x_kernel(const float* __restrict__ x, ushort_t* __restrict__ xb, int n4) {
  int i = blockIdx.x * blockDim.x + threadIdx.x;
  if (i >= n4) return;
  float4 v = ((const float4*)x)[i];
  ushort4 o;
  o.x = f2b(v.x); o.y = f2b(v.y); o.z = f2b(v.z); o.w = f2b(v.w);
  ((ushort4*)xb)[i] = o;
}

// ------- convert + transpose W [512][512] f32 -> WT bf16, LDS-tiled -------
// grid (64, 1, 4): blockIdx.x = nt*8 + kt (64x64 tile), 256 threads
__global__ void cvt_wt_kernel(const float* __restrict__ W0, const float* __restrict__ W1,
                              const float* __restrict__ W2, const float* __restrict__ W3,
                              ushort_t* __restrict__ T0, ushort_t* __restrict__ T1,
                              ushort_t* __restrict__ T2, ushort_t* __restrict__ T3) {
  const float* W; ushort_t* T;
  switch (blockIdx.z) {
    case 0: W = W0; T = T0; break;
    case 1: W = W1; T = T1; break;
    case 2: W = W2; T = T2; break;
    default: W = W3; T = T3; break;
  }
  __shared__ ushort_t Tl[64 * 68];   // [n][k], stride 68 (136B, 8B-aligned rows)
  int t = threadIdx.x;
  int kt = blockIdx.x & 7, nt = blockIdx.x >> 3;
  int krow = t >> 4;          // 0..15
  int ncol = (t & 15) * 4;    // 0..60
#pragma unroll
  for (int j = 0; j < 4; ++j) {
    int k = j * 16 + krow;
    float4 v = *(const float4*)&W[(size_t)(kt * 64 + k) * 512 + nt * 64 + ncol];
    const float* vf = (const float*)&v;
#pragma unroll
    for (int e = 0; e < 4; ++e)
      Tl[(ncol + e) * 68 + k] = f2b(vf[e]);
  }
  __syncthreads();
#pragma unroll
  for (int j = 0; j < 4; ++j) {
    int f = j * 1024 + t * 4;
    int n = f >> 6, k = f & 63;
    *(ushort4*)&T[(size_t)(nt * 64 + n) * 512 + kt * 64 + k] =
        *(const ushort4*)&Tl[n * 68 + k];
  }
}

// ---------------- QKV projection GEMM, m97-style LDS-staged ----------------
// BM=BN=128, BK=64; LDS A/B tiles 16KB each, XOR-swizzled (inverse-swz source,
// linear global_load_lds dest, swz ds_read — rule #21 both-sides discipline).
// z=0 -> Q natural bf16 [8192][512]; z=1 -> K natural; z=2 -> V^T [B*H*Dh][S]
__global__ __launch_bounds__(256) void gemm_qkv_kernel(
    const ushort_t* __restrict__ A,
    const ushort_t* __restrict__ WqT, const ushort_t* __restrict__ WkT,
    const ushort_t* __restrict__ WvT,
    ushort_t* __restrict__ Qo, ushort_t* __restrict__ Ko, ushort_t* __restrict__ VTo) {
  const int K = 512, N = 512, S = 4096;
  const ushort_t* BT; ushort_t* out; int mode;
  switch (blockIdx.z) {
    case 0: BT = WqT; out = Qo;  mode = 0; break;
    case 1: BT = WkT; out = Ko;  mode = 0; break;
    default: BT = WvT; out = VTo; mode = 1; break;
  }
  __shared__ ushort_t Al[128 * 64];
  __shared__ ushort_t Bl[128 * 64];

  int tid = threadIdx.x, lane = tid & 63, w = tid >> 6;
  int g = lane >> 4, ln = lane & 15;
  int wr = w >> 1, wc = w & 1;
  int m0 = blockIdx.y * 128;
  int n0 = blockIdx.x * 128;

  f32x4 acc[4][4];
  const f32x4 zz = {0.f, 0.f, 0.f, 0.f};
#pragma unroll
  for (int i = 0; i < 4; ++i)
#pragma unroll
    for (int j = 0; j < 4; ++j) acc[i][j] = zz;

  for (int kt = 0; kt < 8; ++kt) {
    __syncthreads();   // previous tile's ds_reads complete
#pragma unroll
    for (int i = 0; i < 4; ++i) {
      int p = i * 256 + tid, row = p >> 3, sl = p & 7, sp = sl ^ (row & 7);
      gld_lds16(A + (size_t)(m0 + row) * K + kt * 64 + sp * 8,
                (char*)Al + (i * 256 + (tid & 192)) * 16);
    }
#pragma unroll
    for (int i = 0; i < 4; ++i) {
      int p = i * 256 + tid, row = p >> 3, sl = p & 7, sp = sl ^ (row & 7);
      gld_lds16(BT + (size_t)(n0 + row) * K + kt * 64 + sp * 8,
                (char*)Bl + (i * 256 + (tid & 192)) * 16);
    }
    __syncthreads();   // staging drained (compiler emits vmcnt(0) before barrier)

#pragma unroll
    for (int kc = 0; kc < 2; ++kc) {
      short8 af[4], bf[4];
#pragma unroll
      for (int mt = 0; mt < 4; ++mt) {
        int row = wr * 64 + mt * 16 + ln;
        af[mt] = *(const short8*)((char*)Al + row * 128 + (((kc * 4 + g) ^ (row & 7)) * 16));
      }
#pragma unroll
      for (int nt = 0; nt < 4; ++nt) {
        int row = wc * 64 + nt * 16 + ln;
        bf[nt] = *(const short8*)((char*)Bl + row * 128 + (((kc * 4 + g) ^ (row & 7)) * 16));
      }
#pragma unroll
      for (int mt = 0; mt < 4; ++mt)
#pragma unroll
        for (int nt = 0; nt < 4; ++nt)
          acc[mt][nt] = __builtin_amdgcn_mfma_f32_16x16x32_bf16(af[mt], bf[nt], acc[mt][nt], 0, 0, 0);
    }
  }

  if (mode == 0) {
#pragma unroll
    for (int mt = 0; mt < 4; ++mt)
#pragma unroll
      for (int nt = 0; nt < 4; ++nt)
#pragma unroll
        for (int jj = 0; jj < 4; ++jj) {
          int m = m0 + wr * 64 + mt * 16 + 4 * g + jj;
          int n = n0 + wc * 64 + nt * 16 + ln;
          out[(size_t)m * N + n] = f2b(acc[mt][nt][jj]);
        }
  } else {
#pragma unroll
    for (int mt = 0; mt < 4; ++mt)
#pragma unroll
      for (int nt = 0; nt < 4; ++nt) {
        int s0 = m0 + wr * 64 + mt * 16 + 4 * g;       // 4-aligned, no 4096-straddle
        int u = n0 + wc * 64 + nt * 16 + ln;           // u = h*64 + d
        int b = s0 >> 12, s = s0 & 4095;
        int h = u >> 6, d = u & 63;
        us4 pv;
#pragma unroll
        for (int jj = 0; jj < 4; ++jj) pv[jj] = f2b(acc[mt][nt][jj]);
        *(us4*)&VTo[((size_t)((b * 8 + h) * 64 + d)) * S + s] = pv;
      }
  }
}

// ---------------- output projection GEMM: f32 out, same structure ----------------
__global__ __launch_bounds__(256) void gemm_ao_kernel(
    const ushort_t* __restrict__ A, const ushort_t* __restrict__ BT,
    float* __restrict__ out) {
  const int K = 512, N = 512;
  __shared__ ushort_t Al[128 * 64];
  __shared__ ushort_t Bl[128 * 64];

  int tid = threadIdx.x, lane = tid & 63, w = tid >> 6;
  int g = lane >> 4, ln = lane & 15;
  int wr = w >> 1, wc = w & 1;
  int m0 = blockIdx.y * 128;
  int n0 = blockIdx.x * 128;

  f32x4 acc[4][4];
  const f32x4 zz = {0.f, 0.f, 0.f, 0.f};
#pragma unroll
  for (int i = 0; i < 4; ++i)
#pragma unroll
    for (int j = 0; j < 4; ++j) acc[i][j] = zz;

  for (int kt = 0; kt < 8; ++kt) {
    __syncthreads();
#pragma unroll
    for (int i = 0; i < 4; ++i) {
      int p = i * 256 + tid, row = p >> 3, sl = p & 7, sp = sl ^ (row & 7);
      gld_lds16(A + (size_t)(m0 + row) * K + kt * 64 + sp * 8,
                (char*)Al + (i * 256 + (tid & 192)) * 16);
    }
#pragma unroll
    for (int i = 0; i < 4; ++i) {
      int p = i * 256 + tid, row = p >> 3, sl = p & 7, sp = sl ^ (row & 7);
      gld_lds16(BT + (size_t)(n0 + row) * K + kt * 64 + sp * 8,
                (char*)Bl + (i * 256 + (tid & 192)) * 16);
    }
    __syncthreads();

#pragma unroll
    for (int kc = 0; kc < 2; ++kc) {
      short8 af[4], bf[4];
#pragma unroll
      for (int mt = 0; mt < 4; ++mt) {
        int row = wr * 64 + mt * 16 + ln;
        af[mt] = *(const short8*)((char*)Al + row * 128 + (((kc * 4 + g) ^ (row & 7)) * 16));
      }
#pragma unroll
      for (int nt = 0; nt < 4; ++nt) {
        int row = wc * 64 + nt * 16 + ln;
        bf[nt] = *(const short8*)((char*)Bl + row * 128 + (((kc * 4 + g) ^ (row & 7)) * 16));
      }
#pragma unroll
      for (int mt = 0; mt < 4; ++mt)
#pragma unroll
        for (int nt = 0; nt < 4; ++nt)
          acc[mt][nt] = __builtin_amdgcn_mfma_f32_16x16x32_bf16(af[mt], bf[nt], acc[mt][nt], 0, 0, 0);
    }
  }
#pragma unroll
  for (int mt = 0; mt < 4; ++mt)
#pragma unroll
    for (int nt = 0; nt < 4; ++nt)
#pragma unroll
      for (int jj = 0; jj < 4; ++jj) {
        int m = m0 + wr * 64 + mt * 16 + 4 * g + jj;
        int n = n0 + wc * 64 + nt * 16 + ln;
        out[(size_t)m * N + n] = acc[mt][nt][jj];
      }
}

// ---------------- flash attention ----------------
// grid (S/64, H, B); 4 waves/block; wave w owns q rows [qb*64 + w*16, +16)
// Q,K natural bf16 [B*S][512]; VT bf16 [(b*8+h)*64 + d][4096]; CTX bf16 [B*S][512]
// Softmax in exp2 domain: scores scaled by 0.125*log2(e); identical softmax result.
__global__ __launch_bounds__(256) void attn_kernel(
    const ushort_t* __restrict__ Qg, const ushort_t* __restrict__ Kg,
    const ushort_t* __restrict__ VTg, ushort_t* __restrict__ CTXg) {
  const int S = 4096, U = 512, DH = 64;
  const float CSC = 0.125f * 1.44269504089f;   // scale * log2(e)
  int qb = blockIdx.x, h = blockIdx.y, b = blockIdx.z;
  int tid = threadIdx.x, lane = tid & 63, w = tid >> 6;
  int g = lane >> 4, ln = lane & 15;

  __shared__ ushort_t Kl[64 * 64];
  __shared__ ushort_t Vl[64 * 64];
  __shared__ ushort_t Pl[4][16 * 72];   // stride 72 u16 = 144 B (8B aligned)

  const ushort_t* qp = Qg + ((size_t)b * S + qb * 64 + w * 16 + ln) * U + h * DH + g * 8;
  short8 qf0 = *(const short8*)qp;
  short8 qf1 = *(const short8*)(qp + 32);

  f32x4 acc[4];
  const f32x4 zz = {0.f, 0.f, 0.f, 0.f};
#pragma unroll
  for (int i = 0; i < 4; ++i) acc[i] = zz;
  float mrun = -INFINITY, lrun = 0.f;   // log2-domain running max / sum

  int r = tid >> 3;              // 0..31
  int c8 = (tid & 7) * 8;        // 0,8,..,56
  const ushort_t* kbase = Kg + ((size_t)b * S + r) * U + h * DH + c8;
  const ushort_t* vbase = VTg + ((size_t)((b * 8 + h) * 64 + r)) * S + c8;

  for (int it = 0; it < 64; ++it) {
    int kv0 = it * 64;
    // issue global loads before the barrier (overlap with previous tile's compute)
    uint4 k1 = *(const uint4*)(kbase + (size_t)kv0 * U);
    uint4 k2 = *(const uint4*)(kbase + (size_t)(kv0 + 32) * U);
    uint4 v1 = *(const uint4*)(vbase + kv0);
    uint4 v2 = *(const uint4*)(vbase + (size_t)32 * S + kv0);
    __syncthreads();   // previous tile fully consumed
    {
      int by1 = (r * 128 + c8 * 2) ^ ((r & 7) << 4);
      *(uint4*)((char*)Kl + by1) = k1;
      *(uint4*)((char*)Vl + by1) = v1;
      int r2 = r + 32;
      int by2 = (r2 * 128 + c8 * 2) ^ ((r2 & 7) << 4);
      *(uint4*)((char*)Kl + by2) = k2;
      *(uint4*)((char*)Vl + by2) = v2;
    }
    __syncthreads();   // tile staged

    // ---- S^T = K . Q^T  (rows = kv, cols = q) ----
    f32x4 st[4];
#pragma unroll
    for (int m = 0; m < 4; ++m) {
      int row = m * 16 + ln;
      short8 kf0 = *(const short8*)((char*)Kl + ((row * 128 + 16 * g) ^ ((row & 7) << 4)));
      short8 kf1 = *(const short8*)((char*)Kl + ((row * 128 + 64 + 16 * g) ^ ((row & 7) << 4)));
      st[m] = __builtin_amdgcn_mfma_f32_16x16x32_bf16(kf0, qf0, zz, 0, 0, 0);
      st[m] = __builtin_amdgcn_mfma_f32_16x16x32_bf16(kf1, qf1, st[m], 0, 0, 0);
    }

    // ---- online softmax (exp2 domain); lane owns q-row (lane&15), 16 kv ----
    // raw max, then one scale (CSC > 0 commutes with max)
    float mx0 = fmaxf(fmaxf(st[0][0], st[0][1]), fmaxf(st[0][2], st[0][3]));
    float mx1 = fmaxf(fmaxf(st[1][0], st[1][1]), fmaxf(st[1][2], st[1][3]));
    float mx2 = fmaxf(fmaxf(st[2][0], st[2][1]), fmaxf(st[2][2], st[2][3]));
    float mx3 = fmaxf(fmaxf(st[3][0], st[3][1]), fmaxf(st[3][2], st[3][3]));
    float smax = fmaxf(fmaxf(mx0, mx1), fmaxf(mx2, mx3));
    smax = fmaxf(smax, __shfl_xor(smax, 16));
    smax = fmaxf(smax, __shfl_xor(smax, 32));
    float tmax = smax * CSC;

    // T13 defer-max: skip rescale while growth <= 8 (P bounded by 2^8, f32-safe)
    float mnew = fmaxf(mrun, tmax);
    if (!__all(tmax <= mrun + 8.0f)) {
      float alpha = __builtin_amdgcn_exp2f(mrun - mnew);
      mrun = mnew;
      lrun *= alpha;
      float av[4];
#pragma unroll
      for (int jj = 0; jj < 4; ++jj) av[jj] = __shfl(alpha, 4 * g + jj);
#pragma unroll
      for (int dt = 0; dt < 4; ++dt)
#pragma unroll
        for (int jj = 0; jj < 4; ++jj) acc[dt][jj] *= av[jj];
    }

    // p = exp2(st*CSC - mrun): fma + exp2 per element
    float nb = -mrun;
    float p[16];
    float ps = 0.f;
#pragma unroll
    for (int m = 0; m < 4; ++m)
#pragma unroll
      for (int jj = 0; jj < 4; ++jj) {
        float y = __builtin_amdgcn_exp2f(__builtin_fmaf(st[m][jj], CSC, nb));
        p[m * 4 + jj] = y;
        ps += y;
      }
    ps += __shfl_xor(ps, 16);
    ps += __shfl_xor(ps, 32);
    lrun += ps;

    // P -> LDS via v_cvt_pk_bf16_f32 (2 f32 -> 1 u32), 8B vector stores
#pragma unroll
    for (int m = 0; m < 4; ++m) {
      uint2 pv;
      pv.x = cvtpk(p[m * 4 + 0], p[m * 4 + 1]);
      pv.y = cvtpk(p[m * 4 + 2], p[m * 4 + 3]);
      *(uint2*)&Pl[w][ln * 72 + m * 16 + 4 * g] = pv;
    }
    LDS_FENCE();   // P stores must complete & stay ordered before P frag reads

    // ---- PV: ctx += P . V  (A = P from LDS, B = VT from LDS) ----
#pragma unroll
    for (int c = 0; c < 2; ++c) {
      short8 pf = *(const short8*)&Pl[w][ln * 72 + 32 * c + 8 * g];
#pragma unroll
      for (int dt = 0; dt < 4; ++dt) {
        int row = dt * 16 + ln;
        short8 vf = *(const short8*)((char*)Vl + ((row * 128 + 64 * c + 16 * g) ^ ((row & 7) << 4)));
        acc[dt] = __builtin_amdgcn_mfma_f32_16x16x32_bf16(pf, vf, acc[dt], 0, 0, 0);
      }
    }
  }

  // finalize: divide by row sum (1/lrun via shfl), store ctx bf16 natural layout
  float inv_l = 1.f / lrun;
  float lv[4];
#pragma unroll
  for (int jj = 0; jj < 4; ++jj) lv[jj] = __shfl(inv_l, 4 * g + jj);
#pragma unroll
  for (int dt = 0; dt < 4; ++dt)
#pragma unroll
    for (int jj = 0; jj < 4; ++jj) {
      int s = qb * 64 + w * 16 + 4 * g + jj;
      int u = h * 64 + dt * 16 + ln;
      CTXg[((size_t)b * S + s) * U + u] = f2b(acc[dt][jj] * lv[jj]);
    }
}

extern "C" void kernel_launch(void* const* d_in, const int* in_sizes, int n_in,
                              void* d_out, int out_size, void* d_ws, size_t ws_size,
                              hipStream_t stream) {
  const float* x  = (const float*)d_in[0];
  const float* Wq = (const float*)d_in[1];
  const float* Wk = (const float*)d_in[2];
  const float* Wv = (const float*)d_in[3];
  const float* Wo = (const float*)d_in[4];
  float* out = (float*)d_out;

  ushort_t* ws  = (ushort_t*)d_ws;
  ushort_t* xb  = ws;                 // 4,194,304 elems (reused for CTX later)
  ushort_t* WqT = xb + 4194304;       // 262,144 each
  ushort_t* WkT = WqT + 262144;
  ushort_t* WvT = WkT + 262144;
  ushort_t* WoT = WvT + 262144;
  ushort_t* Qb  = WoT + 262144;       // 4,194,304 each
  ushort_t* Kb  = Qb + 4194304;
  ushort_t* VTb = Kb + 4194304;
  ushort_t* CTX = xb;                 // reuse: xb dead after gemm_qkv

  cvt_x_kernel<<<4096, 256, 0, stream>>>(x, xb, 1048576);
  cvt_wt_kernel<<<dim3(64, 1, 4), 256, 0, stream>>>(Wq, Wk, Wv, Wo, WqT, WkT, WvT, WoT);
  gemm_qkv_kernel<<<dim3(4, 64, 3), 256, 0, stream>>>(xb, WqT, WkT, WvT, Qb, Kb, VTb);
  attn_kernel<<<dim3(64, 8, 2), 256, 0, stream>>>(Qb, Kb, VTb, CTX);
  gemm_ao_kernel<<<dim3(4, 64), 256, 0, stream>>>(CTX, WoT, out);
}

// Round 6
// 249.374 us; speedup vs baseline: 1.2911x; 1.0026x over previous
//
#include <hip/hip_runtime.h>

typedef __attribute__((ext_vector_type(8))) short short8;
typedef __attribute__((ext_vector_type(4))) float f32x4;
typedef __attribute__((ext_vector_type(4))) unsigned short us4;
typedef unsigned short ushort_t;
typedef unsigned int uint_t;

typedef const __attribute__((address_space(1))) void* gas1;
typedef __attribute__((address_space(3))) void* las3;

// fence: forbid compile-time reordering of LDS ops across this point and
// drain outstanding DS ops (rule #18: asm waitcnt needs sched_barrier after)
#define LDS_FENCE()                                            \
  do {                                                         \
    asm volatile("s_waitcnt lgkmcnt(0)" ::: "memory");         \
    __builtin_amdgcn_sched_barrier(0);                         \
  } while (0)

__device__ __forceinline__ ushort_t f2b(float f) {
  union { float f; uint_t u; } v; v.f = f;
  return (ushort_t)((v.u + 0x7fffu + ((v.u >> 16) & 1u)) >> 16);
}

__device__ __forceinline__ float b2f(ushort_t u) {
  union { uint_t u; float f; } v; v.u = ((uint_t)u) << 16;
  return v.f;
}

// pack 2 f32 -> 2 bf16 in one u32 (RNE) — T12 primitive
__device__ __forceinline__ uint_t cvtpk(float lo, float hi) {
  uint_t r;
  asm("v_cvt_pk_bf16_f32 %0, %1, %2" : "=v"(r) : "v"(lo), "v"(hi));
  return r;
}

__device__ __forceinline__ void gld_lds16(const ushort_t* g, void* l) {
  __builtin_amdgcn_global_load_lds((gas1)g, (las3)l, 16, 0, 0);
}

__device__ __forceinline__ float max3f(float a, float b, float c) {
  return fmaxf(fmaxf(a, b), c);   // clang fuses to v_max3_f32
}

// ---------------- convert x: f32 -> bf16, 4 elems/thread ----------------
__global__ void cvt_x_kernel(const float* __restrict__ x, ushort_t* __restrict__ xb, int n4) {
  int i = blockIdx.x * blockDim.x + threadIdx.x;
  if (i >= n4) return;
  float4 v = ((const float4*)x)[i];
  ushort4 o;
  o.x = f2b(v.x); o.y = f2b(v.y); o.z = f2b(v.z); o.w = f2b(v.w);
  ((ushort4*)xb)[i] = o;
}

// ------- convert + transpose W [512][512] f32 -> WT bf16, LDS-tiled -------
// grid (64, 1, 4): blockIdx.x = nt*8 + kt (64x64 tile), 256 threads
__global__ void cvt_wt_kernel(const float* __restrict__ W0, const float* __restrict__ W1,
                              const float* __restrict__ W2, const float* __restrict__ W3,
                              ushort_t* __restrict__ T0, ushort_t* __restrict__ T1,
                              ushort_t* __restrict__ T2, ushort_t* __restrict__ T3) {
  const float* W; ushort_t* T;
  switch (blockIdx.z) {
    case 0: W = W0; T = T0; break;
    case 1: W = W1; T = T1; break;
    case 2: W = W2; T = T2; break;
    default: W = W3; T = T3; break;
  }
  __shared__ ushort_t Tl[64 * 68];   // [n][k], stride 68 (136B, 8B-aligned rows)
  int t = threadIdx.x;
  int kt = blockIdx.x & 7, nt = blockIdx.x >> 3;
  int krow = t >> 4;          // 0..15
  int ncol = (t & 15) * 4;    // 0..60
#pragma unroll
  for (int j = 0; j < 4; ++j) {
    int k = j * 16 + krow;
    float4 v = *(const float4*)&W[(size_t)(kt * 64 + k) * 512 + nt * 64 + ncol];
    const float* vf = (const float*)&v;
#pragma unroll
    for (int e = 0; e < 4; ++e)
      Tl[(ncol + e) * 68 + k] = f2b(vf[e]);
  }
  __syncthreads();
#pragma unroll
  for (int j = 0; j < 4; ++j) {
    int f = j * 1024 + t * 4;
    int n = f >> 6, k = f & 63;
    *(ushort4*)&T[(size_t)(nt * 64 + n) * 512 + kt * 64 + k] =
        *(const ushort4*)&Tl[n * 68 + k];
  }
}

// ---------------- QKV projection GEMM, m97-style LDS-staged ----------------
__global__ __launch_bounds__(256) void gemm_qkv_kernel(
    const ushort_t* __restrict__ A,
    const ushort_t* __restrict__ WqT, const ushort_t* __restrict__ WkT,
    const ushort_t* __restrict__ WvT,
    ushort_t* __restrict__ Qo, ushort_t* __restrict__ Ko, ushort_t* __restrict__ VTo) {
  const int K = 512, N = 512, S = 4096;
  const ushort_t* BT; ushort_t* out; int mode;
  switch (blockIdx.z) {
    case 0: BT = WqT; out = Qo;  mode = 0; break;
    case 1: BT = WkT; out = Ko;  mode = 0; break;
    default: BT = WvT; out = VTo; mode = 1; break;
  }
  __shared__ ushort_t Al[128 * 64];
  __shared__ ushort_t Bl[128 * 64];

  int tid = threadIdx.x, lane = tid & 63, w = tid >> 6;
  int g = lane >> 4, ln = lane & 15;
  int wr = w >> 1, wc = w & 1;
  int m0 = blockIdx.y * 128;
  int n0 = blockIdx.x * 128;

  f32x4 acc[4][4];
  const f32x4 zz = {0.f, 0.f, 0.f, 0.f};
#pragma unroll
  for (int i = 0; i < 4; ++i)
#pragma unroll
    for (int j = 0; j < 4; ++j) acc[i][j] = zz;

  for (int kt = 0; kt < 8; ++kt) {
    __syncthreads();
#pragma unroll
    for (int i = 0; i < 4; ++i) {
      int p = i * 256 + tid, row = p >> 3, sl = p & 7, sp = sl ^ (row & 7);
      gld_lds16(A + (size_t)(m0 + row) * K + kt * 64 + sp * 8,
                (char*)Al + (i * 256 + (tid & 192)) * 16);
    }
#pragma unroll
    for (int i = 0; i < 4; ++i) {
      int p = i * 256 + tid, row = p >> 3, sl = p & 7, sp = sl ^ (row & 7);
      gld_lds16(BT + (size_t)(n0 + row) * K + kt * 64 + sp * 8,
                (char*)Bl + (i * 256 + (tid & 192)) * 16);
    }
    __syncthreads();

#pragma unroll
    for (int kc = 0; kc < 2; ++kc) {
      short8 af[4], bf[4];
#pragma unroll
      for (int mt = 0; mt < 4; ++mt) {
        int row = wr * 64 + mt * 16 + ln;
        af[mt] = *(const short8*)((char*)Al + row * 128 + (((kc * 4 + g) ^ (row & 7)) * 16));
      }
#pragma unroll
      for (int nt = 0; nt < 4; ++nt) {
        int row = wc * 64 + nt * 16 + ln;
        bf[nt] = *(const short8*)((char*)Bl + row * 128 + (((kc * 4 + g) ^ (row & 7)) * 16));
      }
#pragma unroll
      for (int mt = 0; mt < 4; ++mt)
#pragma unroll
        for (int nt = 0; nt < 4; ++nt)
          acc[mt][nt] = __builtin_amdgcn_mfma_f32_16x16x32_bf16(af[mt], bf[nt], acc[mt][nt], 0, 0, 0);
    }
  }

  if (mode == 0) {
#pragma unroll
    for (int mt = 0; mt < 4; ++mt)
#pragma unroll
      for (int nt = 0; nt < 4; ++nt)
#pragma unroll
        for (int jj = 0; jj < 4; ++jj) {
          int m = m0 + wr * 64 + mt * 16 + 4 * g + jj;
          int n = n0 + wc * 64 + nt * 16 + ln;
          out[(size_t)m * N + n] = f2b(acc[mt][nt][jj]);
        }
  } else {
#pragma unroll
    for (int mt = 0; mt < 4; ++mt)
#pragma unroll
      for (int nt = 0; nt < 4; ++nt) {
        int s0 = m0 + wr * 64 + mt * 16 + 4 * g;
        int u = n0 + wc * 64 + nt * 16 + ln;
        int b = s0 >> 12, s = s0 & 4095;
        int h = u >> 6, d = u & 63;
        us4 pv;
#pragma unroll
        for (int jj = 0; jj < 4; ++jj) pv[jj] = f2b(acc[mt][nt][jj]);
        *(us4*)&VTo[((size_t)((b * 8 + h) * 64 + d)) * S + s] = pv;
      }
  }
}

// ---------------- output projection GEMM: f32 out ----------------
__global__ __launch_bounds__(256) void gemm_ao_kernel(
    const ushort_t* __restrict__ A, const ushort_t* __restrict__ BT,
    float* __restrict__ out) {
  const int K = 512, N = 512;
  __shared__ ushort_t Al[128 * 64];
  __shared__ ushort_t Bl[128 * 64];

  int tid = threadIdx.x, lane = tid & 63, w = tid >> 6;
  int g = lane >> 4, ln = lane & 15;
  int wr = w >> 1, wc = w & 1;
  int m0 = blockIdx.y * 128;
  int n0 = blockIdx.x * 128;

  f32x4 acc[4][4];
  const f32x4 zz = {0.f, 0.f, 0.f, 0.f};
#pragma unroll
  for (int i = 0; i < 4; ++i)
#pragma unroll
    for (int j = 0; j < 4; ++j) acc[i][j] = zz;

  for (int kt = 0; kt < 8; ++kt) {
    __syncthreads();
#pragma unroll
    for (int i = 0; i < 4; ++i) {
      int p = i * 256 + tid, row = p >> 3, sl = p & 7, sp = sl ^ (row & 7);
      gld_lds16(A + (size_t)(m0 + row) * K + kt * 64 + sp * 8,
                (char*)Al + (i * 256 + (tid & 192)) * 16);
    }
#pragma unroll
    for (int i = 0; i < 4; ++i) {
      int p = i * 256 + tid, row = p >> 3, sl = p & 7, sp = sl ^ (row & 7);
      gld_lds16(BT + (size_t)(n0 + row) * K + kt * 64 + sp * 8,
                (char*)Bl + (i * 256 + (tid & 192)) * 16);
    }
    __syncthreads();

#pragma unroll
    for (int kc = 0; kc < 2; ++kc) {
      short8 af[4], bf[4];
#pragma unroll
      for (int mt = 0; mt < 4; ++mt) {
        int row = wr * 64 + mt * 16 + ln;
        af[mt] = *(const short8*)((char*)Al + row * 128 + (((kc * 4 + g) ^ (row & 7)) * 16));
      }
#pragma unroll
      for (int nt = 0; nt < 4; ++nt) {
        int row = wc * 64 + nt * 16 + ln;
        bf[nt] = *(const short8*)((char*)Bl + row * 128 + (((kc * 4 + g) ^ (row & 7)) * 16));
      }
#pragma unroll
      for (int mt = 0; mt < 4; ++mt)
#pragma unroll
        for (int nt = 0; nt < 4; ++nt)
          acc[mt][nt] = __builtin_amdgcn_mfma_f32_16x16x32_bf16(af[mt], bf[nt], acc[mt][nt], 0, 0, 0);
    }
  }
#pragma unroll
  for (int mt = 0; mt < 4; ++mt)
#pragma unroll
    for (int nt = 0; nt < 4; ++nt)
#pragma unroll
      for (int jj = 0; jj < 4; ++jj) {
        int m = m0 + wr * 64 + mt * 16 + 4 * g + jj;
        int n = n0 + wc * 64 + nt * 16 + ln;
        out[(size_t)m * N + n] = acc[mt][nt][jj];
      }
}

// ---------------- flash attention, KV-split ----------------
// grid (S/64, H, 2*nparts): z -> {b = z&1, part = z>>1}; 4 waves/block.
// Each block handles ntiles KV tiles; writes NORMALIZED partial ctx (bf16) to
// Obuf[part][bh][s][d] and log2-weight L = m + log2(l) (f32) to Lbuf[part][bh*4096+s].
__global__ __launch_bounds__(256) void attn_kernel(
    const ushort_t* __restrict__ Qg, const ushort_t* __restrict__ Kg,
    const ushort_t* __restrict__ VTg, ushort_t* __restrict__ Obuf,
    float* __restrict__ Lbuf, int ntiles) {
  const int S = 4096, U = 512, DH = 64;
  const float CSC = 0.125f * 1.44269504089f;   // scale * log2(e)
  int qb = blockIdx.x, h = blockIdx.y;
  int b = blockIdx.z & 1, part = blockIdx.z >> 1;
  int bh = b * 8 + h;
  int tid = threadIdx.x, lane = tid & 63, w = tid >> 6;
  int g = lane >> 4, ln = lane & 15;

  __shared__ ushort_t Kl[64 * 64];
  __shared__ ushort_t Vl[64 * 64];
  __shared__ ushort_t Pl[4][16 * 72];

  const ushort_t* qp = Qg + ((size_t)b * S + qb * 64 + w * 16 + ln) * U + h * DH + g * 8;
  short8 qf0 = *(const short8*)qp;
  short8 qf1 = *(const short8*)(qp + 32);

  f32x4 acc[4];
  const f32x4 zz = {0.f, 0.f, 0.f, 0.f};
#pragma unroll
  for (int i = 0; i < 4; ++i) acc[i] = zz;
  float mrun = -INFINITY, lrun = 0.f;

  int r = tid >> 3;              // 0..31
  int c8 = (tid & 7) * 8;        // 0,8,..,56
  const ushort_t* kbase = Kg + ((size_t)b * S + r) * U + h * DH + c8;
  const ushort_t* vbase = VTg + ((size_t)(bh * 64 + r)) * S + c8;

  int it0 = part * ntiles;
  for (int ii = 0; ii < ntiles; ++ii) {
    int kv0 = (it0 + ii) * 64;
    uint4 k1 = *(const uint4*)(kbase + (size_t)kv0 * U);
    uint4 k2 = *(const uint4*)(kbase + (size_t)(kv0 + 32) * U);
    uint4 v1 = *(const uint4*)(vbase + kv0);
    uint4 v2 = *(const uint4*)(vbase + (size_t)32 * S + kv0);
    __syncthreads();
    {
      int by1 = (r * 128 + c8 * 2) ^ ((r & 7) << 4);
      *(uint4*)((char*)Kl + by1) = k1;
      *(uint4*)((char*)Vl + by1) = v1;
      int r2 = r + 32;
      int by2 = (r2 * 128 + c8 * 2) ^ ((r2 & 7) << 4);
      *(uint4*)((char*)Kl + by2) = k2;
      *(uint4*)((char*)Vl + by2) = v2;
    }
    __syncthreads();

    // ---- S^T = K . Q^T ----
    f32x4 st[4];
#pragma unroll
    for (int m = 0; m < 4; ++m) {
      int row = m * 16 + ln;
      short8 kf0 = *(const short8*)((char*)Kl + ((row * 128 + 16 * g) ^ ((row & 7) << 4)));
      short8 kf1 = *(const short8*)((char*)Kl + ((row * 128 + 64 + 16 * g) ^ ((row & 7) << 4)));
      st[m] = __builtin_amdgcn_mfma_f32_16x16x32_bf16(kf0, qf0, zz, 0, 0, 0);
      st[m] = __builtin_amdgcn_mfma_f32_16x16x32_bf16(kf1, qf1, st[m], 0, 0, 0);
    }

    // ---- online softmax (exp2 domain), v_max3 tree ----
    float t0 = max3f(st[0][0], st[0][1], st[0][2]);
    float t1 = max3f(st[0][3], st[1][0], st[1][1]);
    float t2 = max3f(st[1][2], st[1][3], st[2][0]);
    float t3 = max3f(st[2][1], st[2][2], st[2][3]);
    float t4 = max3f(st[3][0], st[3][1], st[3][2]);
    float smax = fmaxf(max3f(t0, t1, t2), max3f(t3, t4, st[3][3]));
    smax = fmaxf(smax, __shfl_xor(smax, 16));
    smax = fmaxf(smax, __shfl_xor(smax, 32));
    float tmax = smax * CSC;

    float mnew = fmaxf(mrun, tmax);
    if (!__all(tmax <= mrun + 8.0f)) {
      float alpha = __builtin_amdgcn_exp2f(mrun - mnew);
      mrun = mnew;
      lrun *= alpha;
      float av[4];
#pragma unroll
      for (int jj = 0; jj < 4; ++jj) av[jj] = __shfl(alpha, 4 * g + jj);
#pragma unroll
      for (int dt = 0; dt < 4; ++dt)
#pragma unroll
        for (int jj = 0; jj < 4; ++jj) acc[dt][jj] *= av[jj];
    }

    float nb = -mrun;
    float p[16];
    float ps = 0.f;
#pragma unroll
    for (int m = 0; m < 4; ++m)
#pragma unroll
      for (int jj = 0; jj < 4; ++jj) {
        float y = __builtin_amdgcn_exp2f(__builtin_fmaf(st[m][jj], CSC, nb));
        p[m * 4 + jj] = y;
        ps += y;
      }
    ps += __shfl_xor(ps, 16);
    ps += __shfl_xor(ps, 32);
    lrun += ps;

#pragma unroll
    for (int m = 0; m < 4; ++m) {
      uint2 pv;
      pv.x = cvtpk(p[m * 4 + 0], p[m * 4 + 1]);
      pv.y = cvtpk(p[m * 4 + 2], p[m * 4 + 3]);
      *(uint2*)&Pl[w][ln * 72 + m * 16 + 4 * g] = pv;
    }
    LDS_FENCE();

    // ---- PV ----
#pragma unroll
    for (int c = 0; c < 2; ++c) {
      short8 pf = *(const short8*)&Pl[w][ln * 72 + 32 * c + 8 * g];
#pragma unroll
      for (int dt = 0; dt < 4; ++dt) {
        int row = dt * 16 + ln;
        short8 vf = *(const short8*)((char*)Vl + ((row * 128 + 64 * c + 16 * g) ^ ((row & 7) << 4)));
        acc[dt] = __builtin_amdgcn_mfma_f32_16x16x32_bf16(pf, vf, acc[dt], 0, 0, 0);
      }
    }
  }

  // store normalized partial + log2 weight
  float inv_l = 1.f / lrun;
  float lv[4];
#pragma unroll
  for (int jj = 0; jj < 4; ++jj) lv[jj] = __shfl(inv_l, 4 * g + jj);
  ushort_t* ob = Obuf + (size_t)part * 4194304 + ((size_t)bh * S) * 64;
#pragma unroll
  for (int dt = 0; dt < 4; ++dt)
#pragma unroll
    for (int jj = 0; jj < 4; ++jj) {
      int s = qb * 64 + w * 16 + 4 * g + jj;
      int d = dt * 16 + ln;
      ob[(size_t)s * 64 + d] = f2b(acc[dt][jj] * lv[jj]);
    }
  if (g == 0) {
    int s = qb * 64 + w * 16 + ln;
    Lbuf[part * 65536 + bh * S + s] = mrun + __log2f(lrun);
  }
}

// ---------------- combine partials -> CTX bf16 natural layout ----------------
// grid 2048 x 256: 32 rows/block, 8 threads/row (8 cols each)
__global__ void combine_kernel(const ushort_t* __restrict__ Obuf,
                               const float* __restrict__ Lbuf,
                               ushort_t* __restrict__ CTX, int nparts) {
  int tid = threadIdx.x;
  int row = blockIdx.x * 32 + (tid >> 3);   // bh*4096 + s
  int c = (tid & 7) * 8;
  int bh = row >> 12, s = row & 4095;
  int b = bh >> 3, h = bh & 7;

  us4 n0a = *(const us4*)&Obuf[(size_t)row * 64 + c];
  us4 n0b = *(const us4*)&Obuf[(size_t)row * 64 + c + 4];
  float o[8];
  if (nparts == 2) {
    float L0 = Lbuf[row];
    float L1 = Lbuf[65536 + row];
    us4 n1a = *(const us4*)&Obuf[(size_t)(4194304 + row * 64) + c];
    us4 n1b = *(const us4*)&Obuf[(size_t)(4194304 + row * 64) + c + 4];
    float Lm = fmaxf(L0, L1);
    float w0 = __builtin_amdgcn_exp2f(L0 - Lm);
    float w1 = __builtin_amdgcn_exp2f(L1 - Lm);
    float inv = 1.f / (w0 + w1);
    float a0 = w0 * inv, a1 = w1 * inv;
#pragma unroll
    for (int j = 0; j < 4; ++j) {
      o[j]     = a0 * b2f(n0a[j]) + a1 * b2f(n1a[j]);
      o[j + 4] = a0 * b2f(n0b[j]) + a1 * b2f(n1b[j]);
    }
  } else {
#pragma unroll
    for (int j = 0; j < 4; ++j) { o[j] = b2f(n0a[j]); o[j + 4] = b2f(n0b[j]); }
  }
  us4 w0v, w1v;
#pragma unroll
  for (int j = 0; j < 4; ++j) { w0v[j] = f2b(o[j]); w1v[j] = f2b(o[j + 4]); }
  ushort_t* dst = &CTX[((size_t)(b * 4096 + s)) * 512 + h * 64 + c];
  *(us4*)dst = w0v;
  *(us4*)(dst + 4) = w1v;
}

extern "C" void kernel_launch(void* const* d_in, const int* in_sizes, int n_in,
                              void* d_out, int out_size, void* d_ws, size_t ws_size,
                              hipStream_t stream) {
  const float* x  = (const float*)d_in[0];
  const float* Wq = (const float*)d_in[1];
  const float* Wk = (const float*)d_in[2];
  const float* Wv = (const float*)d_in[3];
  const float* Wo = (const float*)d_in[4];
  float* out = (float*)d_out;

  ushort_t* ws  = (ushort_t*)d_ws;
  ushort_t* xb  = ws;                 // 8MB (reused for CTX after gemm_qkv)
  ushort_t* WqT = xb + 4194304;
  ushort_t* WkT = WqT + 262144;
  ushort_t* WvT = WkT + 262144;
  ushort_t* WoT = WvT + 262144;
  ushort_t* Qb  = WoT + 262144;
  ushort_t* Kb  = Qb + 4194304;
  ushort_t* VTb = Kb + 4194304;
  ushort_t* Obuf = VTb + 4194304;     // nparts * 8MB
  ushort_t* CTX = xb;

  // need: (17825792 + nparts*4194304)*2 + nparts*262144 bytes
  int nparts = (ws_size >= 52953088u) ? 2 : 1;
  float* Lbuf = (float*)(Obuf + (size_t)nparts * 4194304);
  int ntiles = 64 / nparts;

  cvt_x_kernel<<<4096, 256, 0, stream>>>(x, xb, 1048576);
  cvt_wt_kernel<<<dim3(64, 1, 4), 256, 0, stream>>>(Wq, Wk, Wv, Wo, WqT, WkT, WvT, WoT);
  gemm_qkv_kernel<<<dim3(4, 64, 3), 256, 0, stream>>>(xb, WqT, WkT, WvT, Qb, Kb, VTb);
  attn_kernel<<<dim3(64, 8, 2 * nparts), 256, 0, stream>>>(Qb, Kb, VTb, Obuf, Lbuf, ntiles);
  combine_kernel<<<2048, 256, 0, stream>>>(Obuf, Lbuf, CTX, nparts);
  gemm_ao_kernel<<<dim3(4, 64), 256, 0, stream>>>(CTX, WoT, out);
}